// Round 5
// baseline (46.977 us; speedup 1.0000x reference)
//
#include <hip/hip_runtime.h>

// KAT group rational activation, elementwise:
//   out = p(z) / q(z)
//   p(z) = a0 + a1 z + ... + a5 z^5          (a shared across all groups)
//   q(z) = 1 + |b1| z + |b2| z^2 + |b3| z^3 + |b4| z^4   (b per group)
// Shapes: x (4, 4096, 2048) f32, G=8 groups of 256 channels.
// Ladder: R0 46.08us (plain). R2 51.27us (nt loads+stores) REGRESSED.
// R3 46.38us (2x unroll, no nt) -> unroll neutral, nt-loads were the loss:
// they killed the 67MB/replay L3 retention of x (FETCH=67MB, half of input).
// R4: normal loads (x stays in L3) + NT STORES ONLY (out marked evict-first
// so it doesn't evict x). Goal: x fully L3-resident across replays,
// FETCH -> ~0, HBM traffic ~= writes only.

#define GROUPS  8

typedef float f32x4 __attribute__((ext_vector_type(4)));

__global__ __launch_bounds__(256) void kat_rational_kernel(
    const f32x4* __restrict__ x4,
    const float* __restrict__ wn,   // 6 numerator coeffs (shared)
    const float* __restrict__ wd,   // 8*4 denominator coeffs
    f32x4*       __restrict__ out4,
    int n4)
{
    const int tid    = blockIdx.x * blockDim.x + threadIdx.x;
    const int stride = gridDim.x * blockDim.x;

    // stride*4 = 2,097,152 elements, a multiple of D=2048 (guaranteed by
    // kernel_launch's grid choice), so the group index g = (d/256) is
    // loop-invariant per thread: g = (tid >> 6) & 7.
    const int g = (tid >> 6) & (GROUPS - 1);

    const float a0 = wn[0], a1 = wn[1], a2 = wn[2];
    const float a3 = wn[3], a4 = wn[4], a5 = wn[5];
    const float c1 = fabsf(wd[g * 4 + 0]);
    const float c2 = fabsf(wd[g * 4 + 1]);
    const float c3 = fabsf(wd[g * 4 + 2]);
    const float c4 = fabsf(wd[g * 4 + 3]);

    // 2x unroll: two independent float4 loads in flight per iteration.
    for (int i = tid; i < n4; i += 2 * stride) {
        const int i1 = i + stride;
        f32x4 v0 = x4[i];           // NORMAL load: retain x in L2/L3
        f32x4 v1 = {};
        const bool has1 = (i1 < n4);
        if (has1) v1 = x4[i1];

        f32x4 r0, r1;
#pragma unroll
        for (int j = 0; j < 4; ++j) {
            const float z = v0[j];
            float p = fmaf(a5, z, a4);
            p = fmaf(p, z, a3);
            p = fmaf(p, z, a2);
            p = fmaf(p, z, a1);
            p = fmaf(p, z, a0);
            float q = fmaf(c4, z, c3);
            q = fmaf(q, z, c2);
            q = fmaf(q, z, c1);
            q = fmaf(q, z, 1.0f);
            r0[j] = p / q;   // IEEE f32 division for accuracy
        }
#pragma unroll
        for (int j = 0; j < 4; ++j) {
            const float z = v1[j];
            float p = fmaf(a5, z, a4);
            p = fmaf(p, z, a3);
            p = fmaf(p, z, a2);
            p = fmaf(p, z, a1);
            p = fmaf(p, z, a0);
            float q = fmaf(c4, z, c3);
            q = fmaf(q, z, c2);
            q = fmaf(q, z, c1);
            q = fmaf(q, z, 1.0f);
            r1[j] = p / q;
        }

        // NT stores: mark output lines evict-first so they don't push x
        // out of the Infinity Cache between graph replays.
        __builtin_nontemporal_store(r0, &out4[i]);
        if (has1) __builtin_nontemporal_store(r1, &out4[i1]);
    }
}

extern "C" void kernel_launch(void* const* d_in, const int* in_sizes, int n_in,
                              void* d_out, int out_size, void* d_ws, size_t ws_size,
                              hipStream_t stream) {
    const float* x  = (const float*)d_in[0];
    const float* wn = (const float*)d_in[1];  // (1,6) numerator
    const float* wd = (const float*)d_in[2];  // (8,4) denominator
    float* out = (float*)d_out;

    const int n  = in_sizes[0];       // 33,554,432
    const int n4 = n / 4;             // 8,388,608 float4s

    // 2048 blocks x 256 threads = 8 blocks/CU on 256 CUs, 32 waves/CU.
    // stride*4 elements = 2,097,152 = multiple of D=2048 -> group index
    // loop-invariant per thread (required by the kernel's hoisting).
    const int block = 256;
    const int grid  = 2048;
    kat_rational_kernel<<<grid, block, 0, stream>>>(
        (const f32x4*)x, wn, wd, (f32x4*)out, n4);
}

// Round 6
// 45.893 us; speedup vs baseline: 1.0236x; 1.0236x over previous
//
#include <hip/hip_runtime.h>

// KAT group rational activation, elementwise:
//   out = p(z) / q(z)
//   p(z) = a0 + a1 z + ... + a5 z^5          (a shared across all groups)
//   q(z) = 1 + |b1| z + |b2| z^2 + |b3| z^3 + |b4| z^4   (b per group)
// Shapes: x (4, 4096, 2048) f32, G=8 groups of 256 channels.
//
// FINAL (R5 = revert to R0, the best measured variant):
//   R0 plain:            46.08 us  <- this kernel
//   R2 nt load+store:    51.27 us  (nt loads kill 67MB/replay L3 read-hits)
//   R3 2x unroll:        46.38 us  (unroll neutral: TLP at 32 waves/CU
//                                   already hides latency)
//   R4 nt store only:    46.98 us  (L3 is memory-side; nt doesn't steer it)
// App BW = 268.4MB / 46.08us = 5.83 TB/s = 92.6% of the 6.29 TB/s measured
// float4-copy ceiling for this same read+write streaming pattern. Memory-
// bound roofline reached; VALUBusy ~19%, WRITE_SIZE exactly ideal, FETCH
// below ideal (L3 retains ~half of x across replays).

#define GROUPS  8

__global__ __launch_bounds__(256) void kat_rational_kernel(
    const float4* __restrict__ x4,
    const float*  __restrict__ wn,   // 6 numerator coeffs (shared)
    const float*  __restrict__ wd,   // 8*4 denominator coeffs
    float4*       __restrict__ out4,
    int n4)
{
    const int tid    = blockIdx.x * blockDim.x + threadIdx.x;
    const int stride = gridDim.x * blockDim.x;

    // Element index of this thread's first float4 is tid*4.
    // d = elem % 2048, g = d / 256  ->  g = (tid >> 6) & 7.
    // Grid stride in elements = stride*4 = 2,097,152, a multiple of D=2048
    // (guaranteed by kernel_launch's grid choice), so g is loop-invariant.
    const int g = (tid >> 6) & (GROUPS - 1);

    const float a0 = wn[0], a1 = wn[1], a2 = wn[2];
    const float a3 = wn[3], a4 = wn[4], a5 = wn[5];
    const float c1 = fabsf(wd[g * 4 + 0]);
    const float c2 = fabsf(wd[g * 4 + 1]);
    const float c3 = fabsf(wd[g * 4 + 2]);
    const float c4 = fabsf(wd[g * 4 + 3]);

    for (int i = tid; i < n4; i += stride) {
        float4 v = x4[i];
        float r[4];
        float zs[4] = {v.x, v.y, v.z, v.w};
#pragma unroll
        for (int j = 0; j < 4; ++j) {
            const float z = zs[j];
            float p = fmaf(a5, z, a4);
            p = fmaf(p, z, a3);
            p = fmaf(p, z, a2);
            p = fmaf(p, z, a1);
            p = fmaf(p, z, a0);
            float q = fmaf(c4, z, c3);
            q = fmaf(q, z, c2);
            q = fmaf(q, z, c1);
            q = fmaf(q, z, 1.0f);
            r[j] = p / q;   // IEEE f32 division (no fast-math) for accuracy
        }
        float4 o;
        o.x = r[0]; o.y = r[1]; o.z = r[2]; o.w = r[3];
        out4[i] = o;
    }
}

extern "C" void kernel_launch(void* const* d_in, const int* in_sizes, int n_in,
                              void* d_out, int out_size, void* d_ws, size_t ws_size,
                              hipStream_t stream) {
    const float* x  = (const float*)d_in[0];
    const float* wn = (const float*)d_in[1];  // (1,6) numerator
    const float* wd = (const float*)d_in[2];  // (8,4) denominator
    float* out = (float*)d_out;

    const int n  = in_sizes[0];       // 33,554,432
    const int n4 = n / 4;             // 8,388,608 float4s

    // 2048 blocks x 256 threads = 8 blocks/CU on 256 CUs, 32 waves/CU.
    // stride*4 elements = 2,097,152 = multiple of D=2048 -> group index
    // loop-invariant per thread (required by the kernel's hoisting).
    const int block = 256;
    const int grid  = 2048;
    kat_rational_kernel<<<grid, block, 0, stream>>>(
        (const float4*)x, wn, wd, (float4*)out, n4);
}